// Round 2
// baseline (5081.020 us; speedup 1.0000x reference)
//
#include <hip/hip_runtime.h>
#include <stdint.h>

// Residual VQ, MI355X. N=16384 rows, D=256, K=4096 codes, Q=4 stages.
// residual value never changes => all stages quantize zn=l2norm(x).
// 1-pass fp16 hi*hi MFMA scoring (codebook is unit-norm => rank by dot),
// top-3+top-2-idx tracking, exact fp32 rescore of top-2 when gap12<MARGIN,
// full exact rescan when gap13<MARGIN (soundness guard).

#define NR 16384
#define DIM 256
#define KCB 4096
#define QST 4
#define MARGIN_DOT 1.25e-3f
#define CAP_RESCAN 16384
#define CAP_RESCORE 32768

typedef _Float16 f16;
typedef __attribute__((ext_vector_type(4))) f16 f16x4;
typedef __attribute__((ext_vector_type(8))) f16 f16x8;
typedef __attribute__((ext_vector_type(4))) float f32x4;

// ---- workspace byte offsets (~19 MB) ----
#define WS_ZN_HI   ((size_t)0)                        // NR*DIM f16 = 8 MB
#define WS_CB_HI   ((size_t)8*1024*1024)              // Q*K*DIM f16 = 8 MB
#define WS_NORMS   ((size_t)16*1024*1024)             // NR f32 (64KB)
#define WS_SSQ     (WS_NORMS + 65536)                 // Q*K f32 (64KB)
#define WS_TOPS    (WS_SSQ + 65536)                   // Q*NR*2 float4 = 2 MB
#define WS_IDX     (WS_TOPS + (size_t)QST*NR*2*16)    // NR*Q int (256KB)
#define WS_LIST    (WS_IDX + (size_t)QST*NR*4)        // rescan list (ints)
#define WS_LIST2   (WS_LIST + (size_t)CAP_RESCAN*4)   // rescore list (int2)
#define WS_CNT     (WS_LIST2 + (size_t)CAP_RESCORE*8) // 2 counters
#define WS_PART    (WS_CNT + 16)                      // 4096 f32 loss partials

__device__ __forceinline__ void gll16(const void* g, void* l) {
  __builtin_amdgcn_global_load_lds(
      (const __attribute__((address_space(1))) void*)g,
      (__attribute__((address_space(3))) void*)l, 16, 0, 0);
}

// shared exact-dot helper: identical accumulation order in both exact paths
__device__ __forceinline__ float dot4chain(const float4* __restrict__ c,
                                           const float4* __restrict__ z) {
  float dot = 0.f;
  for (int d = 0; d < 64; ++d) {
    const float4 cv = c[d], zv = z[d];
    dot += cv.x * zv.x + cv.y * zv.y + cv.z * zv.z + cv.w * zv.w;
  }
  return dot;
}

// ---- prep: per-row sumsq (+l2norm for x), fp16 hi split; combined launch ----
__global__ void prep_kernel(const float* __restrict__ x, const float* __restrict__ cb,
                            char* __restrict__ ws) {
  const int w = threadIdx.x >> 6, lane = threadIdx.x & 63;
  const int normalize = (blockIdx.x < (NR / 4));
  const int blk = normalize ? blockIdx.x : blockIdx.x - (NR / 4);
  const float* src = normalize ? x : cb;
  const int row = blk * 4 + w;
  const float4 v = ((const float4*)src)[row * 64 + lane];
  float ss = v.x * v.x + v.y * v.y + v.z * v.z + v.w * v.w;
#pragma unroll
  for (int m = 32; m; m >>= 1) ss += __shfl_xor(ss, m);
  float4 z = v;
  f16* hi;
  if (normalize) {
    const float denom = fmaxf(sqrtf(ss), 1e-12f);
    z.x = v.x / denom; z.y = v.y / denom; z.z = v.z / denom; z.w = v.w / denom;
    hi = (f16*)(ws + WS_ZN_HI);
    if (lane == 0) ((float*)(ws + WS_NORMS))[row] = denom;
    if (blockIdx.x == 0 && threadIdx.x == 0) {
      ((int*)(ws + WS_CNT))[0] = 0;
      ((int*)(ws + WS_CNT))[1] = 0;
    }
  } else {
    hi = (f16*)(ws + WS_CB_HI);
    if (lane == 0) ((float*)(ws + WS_SSQ))[row] = ss;
  }
  f16x4 h;
  h[0] = (f16)z.x; h[1] = (f16)z.y; h[2] = (f16)z.z; h[3] = (f16)z.w;
  ((f16x4*)hi)[row * 64 + lane] = h;
}

// ---- score: 1-pass hi*hi GEMM + per-row top3(+2 idx) over K ----
__launch_bounds__(256, 2)
__global__ void score_kernel(char* __restrict__ ws) {
  // LDS: [0]=A_hi [1]=B_hi, each [128 rows][64 halfs] = 32 KB total
  __shared__ __align__(16) f16 smem[2][128][64];
  const int tid = threadIdx.x, w = tid >> 6, lane = tid & 63;
  const int wr = w >> 1, wc = w & 1;
  const int blk = blockIdx.x;
  const int xcd = blk & 7, st = xcd >> 1;
  const int rowtile = ((xcd & 1) << 6) + (blk >> 3);   // 0..127
  const int rowBase = rowtile << 7;

  const f16* zn_hi = (const f16*)(ws + WS_ZN_HI);
  const f16* cb_hi = (const f16*)(ws + WS_CB_HI);

  // staging roles: waves 0,1 -> A halves; waves 2,3 -> B halves
  const int reg = w >> 1;            // 0=A, 1=B
  const int half = w & 1;            // which 64-row half
  const f16* src = reg ? cb_hi : zn_hi;
  // pre-swizzled global source: LDS[row][slot] holds granule (slot ^ (row&7))
  const int g0 = (lane & 7) ^ ((lane >> 3) & 7);
  const size_t laneOff = (size_t)(lane >> 3) * DIM + (size_t)g0 * 8;
  f16* ldsW = &smem[reg][half * 64][0];

  float t1[16], t2[16], t3[16]; int ip[16];
#pragma unroll
  for (int s = 0; s < 16; ++s) { t1[s] = -3.4e38f; t2[s] = -3.4e38f; t3[s] = -3.4e38f; ip[s] = 0; }
  const int colLane = wc * 64 + (lane & 15);

  for (int ct = 0; ct < 32; ++ct) {
    f32x4 acc[4][4];
#pragma unroll
    for (int m = 0; m < 4; ++m)
#pragma unroll
      for (int n = 0; n < 4; ++n) { acc[m][n][0] = 0.f; acc[m][n][1] = 0.f; acc[m][n][2] = 0.f; acc[m][n][3] = 0.f; }

    const int rowG0 = (reg ? (st * KCB + ct * 128) : rowBase) + half * 64;
    const f16* srcBase = src + (size_t)rowG0 * DIM + laneOff;

    for (int dc = 0; dc < 4; ++dc) {
      __syncthreads();  // protect LDS reuse from previous iteration's reads
      const f16* sp = srcBase + dc * 64;
#pragma unroll
      for (int op = 0; op < 8; ++op)
        gll16(sp + op * 8 * DIM, ldsW + op * 512);
      __syncthreads();  // compiler drains vmcnt before barrier

#pragma unroll
      for (int kk = 0; kk < 2; ++kk) {
        f16x8 ah[4];
#pragma unroll
        for (int m = 0; m < 4; ++m) {
          const int rl = wr * 64 + m * 16 + (lane & 15);
          const int slot = ((kk << 2) + (lane >> 4)) ^ (rl & 7);
          ah[m] = *(const f16x8*)(&smem[0][0][0] + rl * 64 + slot * 8);
        }
#pragma unroll
        for (int n = 0; n < 4; ++n) {
          const int cl = wc * 64 + n * 16 + (lane & 15);
          const int slot = ((kk << 2) + (lane >> 4)) ^ (cl & 7);
          const f16x8 bh = *(const f16x8*)(&smem[1][0][0] + cl * 64 + slot * 8);
#pragma unroll
          for (int m = 0; m < 4; ++m)
            acc[m][n] = __builtin_amdgcn_mfma_f32_16x16x32_f16(ah[m], bh, acc[m][n], 0, 0, 0);
        }
      }
    }
    // rank by raw dot (codebook unit-norm => ssq const). top3 + packed top2 idx.
#pragma unroll
    for (int m = 0; m < 4; ++m)
#pragma unroll
      for (int r = 0; r < 4; ++r) {
        const int sl = m * 4 + r;
        const float m4 = fmaxf(fmaxf(acc[m][0][r], acc[m][1][r]),
                               fmaxf(acc[m][2][r], acc[m][3][r]));
        if (m4 > t3[sl]) {
#pragma unroll
          for (int n = 0; n < 4; ++n) {
            const float sc = acc[m][n][r];
            if (sc > t3[sl]) {
              const int col = ct * 128 + n * 16 + colLane;
              if (sc > t1[sl])      { t3[sl] = t2[sl]; t2[sl] = t1[sl]; t1[sl] = sc; ip[sl] = (col << 12) | (ip[sl] >> 12); }
              else if (sc > t2[sl]) { t3[sl] = t2[sl]; t2[sl] = sc; ip[sl] = (ip[sl] & ~0xFFF) | col; }
              else                  { t3[sl] = sc; }
            }
          }
        }
      }
  }

  // butterfly merge across the 16 lanes holding the same row
  float4* tops = (float4*)(ws + WS_TOPS);
#pragma unroll
  for (int m = 0; m < 4; ++m)
#pragma unroll
    for (int r = 0; r < 4; ++r) {
      const int sl = m * 4 + r;
      float a1 = t1[sl], a2 = t2[sl], a3 = t3[sl]; int aip = ip[sl];
#pragma unroll
      for (int msk = 1; msk < 16; msk <<= 1) {
        const float b1 = __shfl_xor(a1, msk);
        const float b2 = __shfl_xor(a2, msk);
        const float b3 = __shfl_xor(a3, msk);
        const int bip = __shfl_xor(aip, msk);
        const int ai1 = aip >> 12, bi1 = bip >> 12;
        const bool tA = (a1 > b1) || (a1 == b1 && ai1 <= bi1);
        const float x1 = tA ? a1 : b1, x2 = tA ? a2 : b2, x3 = tA ? a3 : b3;
        const int xip = tA ? aip : bip;
        const float y1 = tA ? b1 : a1, y2 = tA ? b2 : a2;
        const int yip = tA ? bip : aip;
        const int xi2 = xip & 0xFFF, yi1 = yip >> 12;
        const bool tB = (x2 > y1) || (x2 == y1 && xi2 <= yi1);
        const float n2 = tB ? x2 : y1;
        const int ni2 = tB ? xi2 : yi1;
        const float n3 = tB ? fmaxf(x3, y1) : fmaxf(x2, y2);
        a1 = x1; a2 = n2; a3 = n3; aip = (xip & 0xFFF000) | ni2;
      }
      if ((lane & 15) == 0) {
        const int row = rowBase + wr * 64 + m * 16 + (lane >> 4) * 4 + r;
        tops[((size_t)st * NR + row) * 2 + wc] =
            make_float4(a1, a2, a3, __int_as_float(aip));
      }
    }
}

// ---- merge wave-halves, pick index, flag rescore / rescan ----
__global__ void merge_flag_kernel(char* __restrict__ ws) {
  const int t = blockIdx.x * 256 + threadIdx.x;  // t = row*4 + stage
  const int row = t >> 2, st = t & 3;
  const float4* tops = (const float4*)(ws + WS_TOPS);
  const float4 A = tops[((size_t)st * NR + row) * 2 + 0];
  const float4 B = tops[((size_t)st * NR + row) * 2 + 1];
  const float a1 = A.x, a2 = A.y, a3 = A.z; const int aip = __float_as_int(A.w);
  const float b1 = B.x, b2 = B.y, b3 = B.z; const int bip = __float_as_int(B.w);
  const int ai1 = aip >> 12, bi1 = bip >> 12;
  const bool tA = (a1 > b1) || (a1 == b1 && ai1 <= bi1);
  const float x1 = tA ? a1 : b1, x2 = tA ? a2 : b2, x3 = tA ? a3 : b3;
  const int xip = tA ? aip : bip;
  const float y1 = tA ? b1 : a1, y2 = tA ? b2 : a2;
  const int yip = tA ? bip : aip;
  const int xi2 = xip & 0xFFF, yi1 = yip >> 12;
  const bool tB = (x2 > y1) || (x2 == y1 && xi2 <= yi1);
  const float v2 = tB ? x2 : y1;
  const int vi2 = tB ? xi2 : yi1;
  const float v3 = tB ? fmaxf(x3, y1) : fmaxf(x2, y2);
  const float v1 = x1; const int vi1 = xip >> 12;

  ((int*)(ws + WS_IDX))[t] = vi1;
  const bool rescan = (v1 - v3 < MARGIN_DOT);
  const bool rescore = !rescan && (v1 - v2 < MARGIN_DOT);
  if (rescan) {
    const int p = atomicAdd((int*)(ws + WS_CNT), 1);
    if (p < CAP_RESCAN) ((int*)(ws + WS_LIST))[p] = t;
  } else if (rescore) {
    const int p = atomicAdd((int*)(ws + WS_CNT) + 1, 1);
    if (p < CAP_RESCORE) ((int2*)(ws + WS_LIST2))[p] = make_int2(t, (vi1 << 12) | vi2);
  }
}

// ---- exact fp32 rescore of the two candidates (one thread per item) ----
__global__ void rescore_kernel(const float* __restrict__ x, const float* __restrict__ cb,
                               char* __restrict__ ws) {
  const int j = blockIdx.x * 256 + threadIdx.x;
  const int cnt = min(((const int*)(ws + WS_CNT))[1], CAP_RESCORE);
  if (j >= cnt) return;
  const int2 e = ((const int2*)(ws + WS_LIST2))[j];
  const int t = e.x, row = t >> 2, st = t & 3;
  const int i1 = e.y >> 12, i2 = e.y & 0xFFF;
  const float denom = ((const float*)(ws + WS_NORMS))[row];
  const float* ssqp = (const float*)(ws + WS_SSQ) + (size_t)st * KCB;

  float zrow[DIM];
  float zsq = 0.f;
  const float4* x4 = (const float4*)(x + (size_t)row * DIM);
  for (int d = 0; d < 64; ++d) {
    float4 xv = x4[d];
    xv.x /= denom; xv.y /= denom; xv.z /= denom; xv.w /= denom;
    ((float4*)zrow)[d] = xv;
    zsq += xv.x * xv.x + xv.y * xv.y + xv.z * xv.z + xv.w * xv.w;
  }
  const float* cbs = cb + (size_t)st * KCB * DIM;
  const float dot1 = dot4chain((const float4*)(cbs + (size_t)i1 * DIM), (const float4*)zrow);
  const float dot2 = dot4chain((const float4*)(cbs + (size_t)i2 * DIM), (const float4*)zrow);
  const float d1 = (zsq + ssqp[i1]) - 2.0f * dot1;
  const float d2 = (zsq + ssqp[i2]) - 2.0f * dot2;
  const int winner = (d2 < d1 || (d2 == d1 && i2 < i1)) ? i2 : i1;
  ((int*)(ws + WS_IDX))[t] = winner;
}

// ---- exact fp32 full re-scan for guard-flagged (row,stage) ----
__global__ void rescue_kernel(const float* __restrict__ x, const float* __restrict__ cb,
                              char* __restrict__ ws) {
  __shared__ float zrow[DIM];
  __shared__ float bv[256];
  __shared__ int bi[256];
  const int tid = threadIdx.x;
  int cnt = ((const int*)(ws + WS_CNT))[0];
  if (cnt > CAP_RESCAN) cnt = CAP_RESCAN;
  for (int i = blockIdx.x; i < cnt; i += gridDim.x) {
    const int t = ((const int*)(ws + WS_LIST))[i];
    const int row = t >> 2, st = t & 3;
    const float denom = ((const float*)(ws + WS_NORMS))[row];
    zrow[tid] = x[(size_t)row * DIM + tid] / denom;
    __syncthreads();
    float zs = zrow[tid] * zrow[tid];
#pragma unroll
    for (int m = 32; m; m >>= 1) zs += __shfl_xor(zs, m);
    if ((tid & 63) == 0) bv[tid >> 6] = zs;
    __syncthreads();
    const float zsq = bv[0] + bv[1] + bv[2] + bv[3];
    __syncthreads();

    const float* cbs = cb + (size_t)st * KCB * DIM;
    const float* ssqp = (const float*)(ws + WS_SSQ) + (size_t)st * KCB;
    float best = 3.4e38f; int bidx = 0x7fffffff;
    for (int k = tid; k < KCB; k += 256) {
      const float dot = dot4chain((const float4*)(cbs + (size_t)k * DIM), (const float4*)zrow);
      const float aa = zsq + ssqp[k];        // match numpy: (zsq+ssq) - 2*dot
      const float dist = aa - 2.0f * dot;
      if (dist < best) { best = dist; bidx = k; }
    }
    bv[tid] = best; bi[tid] = bidx;
    __syncthreads();
    for (int off = 128; off; off >>= 1) {
      if (tid < off) {
        if (bv[tid + off] < bv[tid] ||
            (bv[tid + off] == bv[tid] && bi[tid + off] < bi[tid])) {
          bv[tid] = bv[tid + off]; bi[tid] = bi[tid + off];
        }
      }
      __syncthreads();
    }
    if (tid == 0) ((int*)(ws + WS_IDX))[t] = bi[0];
    __syncthreads();
  }
}

// ---- gather codewords, quantized sum, loss partials, indices(as float) ----
__global__ void finalize_kernel(const float* __restrict__ x, const float* __restrict__ cb,
                                char* __restrict__ ws, float* __restrict__ out) {
  __shared__ float wsum[4];
  const int w = threadIdx.x >> 6, lane = threadIdx.x & 63;
  const int row = blockIdx.x * 4 + w;
  const int* idxp = (const int*)(ws + WS_IDX) + (size_t)row * 4;
  const float denom = ((const float*)(ws + WS_NORMS))[row];
  const float4 xv = ((const float4*)x)[row * 64 + lane];
  const float4 zn = make_float4(xv.x / denom, xv.y / denom, xv.z / denom, xv.w / denom);
  float4 s = make_float4(0.f, 0.f, 0.f, 0.f);
  float lacc = 0.f;
#pragma unroll
  for (int q = 0; q < 4; ++q) {
    const int id = idxp[q];
    const float4 e = ((const float4*)(cb + ((size_t)q * KCB + id) * DIM))[lane];
    s.x += e.x; s.y += e.y; s.z += e.z; s.w += e.w;
    const float dx = e.x - zn.x, dy = e.y - zn.y, dz = e.z - zn.z, dw = e.w - zn.w;
    lacc += dx * dx + dy * dy + dz * dz + dw * dw;
  }
  ((float4*)out)[row * 64 + lane] = s;
  if (lane < 4) out[4194305 + (size_t)row * 4 + lane] = (float)idxp[lane];
#pragma unroll
  for (int m = 32; m; m >>= 1) lacc += __shfl_xor(lacc, m);
  if (lane == 0) wsum[w] = lacc;
  __syncthreads();
  if (threadIdx.x == 0)
    ((float*)(ws + WS_PART))[blockIdx.x] = wsum[0] + wsum[1] + wsum[2] + wsum[3];
}

__global__ void loss_final_kernel(const char* __restrict__ ws, float* __restrict__ out) {
  __shared__ float wsum[4];
  const int tid = threadIdx.x, w = tid >> 6, lane = tid & 63;
  const float* p = (const float*)(ws + WS_PART);
  float s = 0.f;
  for (int i = tid; i < 4096; i += 256) s += p[i];
#pragma unroll
  for (int m = 32; m; m >>= 1) s += __shfl_xor(s, m);
  if (lane == 0) wsum[w] = s;
  __syncthreads();
  if (tid == 0)
    out[4194304] = (wsum[0] + wsum[1] + wsum[2] + wsum[3]) * (1.0f / 4194304.0f);
}

extern "C" void kernel_launch(void* const* d_in, const int* in_sizes, int n_in,
                              void* d_out, int out_size, void* d_ws, size_t ws_size,
                              hipStream_t stream) {
  (void)in_sizes; (void)n_in; (void)out_size; (void)ws_size;
  const float* x = (const float*)d_in[0];
  const float* cb = (const float*)d_in[1];
  float* out = (float*)d_out;
  char* ws = (char*)d_ws;

  hipLaunchKernelGGL(prep_kernel, dim3(NR / 2), dim3(256), 0, stream, x, cb, ws);
  hipLaunchKernelGGL(score_kernel, dim3(512), dim3(256), 0, stream, ws);
  hipLaunchKernelGGL(merge_flag_kernel, dim3((NR * QST) / 256), dim3(256), 0, stream, ws);
  hipLaunchKernelGGL(rescore_kernel, dim3(CAP_RESCORE / 256), dim3(256), 0, stream, x, cb, ws);
  hipLaunchKernelGGL(rescue_kernel, dim3(256), dim3(256), 0, stream, x, cb, ws);
  hipLaunchKernelGGL(finalize_kernel, dim3(NR / 4), dim3(256), 0, stream, x, cb, ws, out);
  hipLaunchKernelGGL(loss_final_kernel, dim3(1), dim3(256), 0, stream, ws, out);
}

// Round 3
// 430.733 us; speedup vs baseline: 11.7962x; 11.7962x over previous
//
#include <hip/hip_runtime.h>
#include <stdint.h>

// Residual VQ, MI355X. N=16384 rows, D=256, K=4096 codes, Q=4 stages.
// residual value never changes => all stages quantize zn=l2norm(x).
// 1-pass fp16 hi*hi MFMA scoring (codebook unit-norm => rank by raw dot),
// round-1-proven top-2 tracking (t1,t2,i1 register shape), margin flag ->
// stage-bucketed 8-row-batched exact fp32 rescue (numpy-faithful chain dots).

#define NR 16384
#define DIM 256
#define KCB 4096
#define QST 4
#define MARGIN_DOT 4e-4f

typedef _Float16 f16;
typedef __attribute__((ext_vector_type(4))) f16 f16x4;
typedef __attribute__((ext_vector_type(8))) f16 f16x8;
typedef __attribute__((ext_vector_type(4))) float f32x4;

// ---- workspace byte offsets (~18.7 MB) ----
#define WS_ZN_HI   ((size_t)0)                        // NR*DIM f16 = 8 MB
#define WS_CB_HI   ((size_t)8*1024*1024)              // Q*K*DIM f16 = 8 MB
#define WS_NORMS   ((size_t)16*1024*1024)             // NR f32 (64KB)
#define WS_SSQ     (WS_NORMS + 65536)                 // Q*K f32 (64KB)
#define WS_TOPS    (WS_SSQ + 65536)                   // Q*NR*2 float4 = 2 MB
#define WS_IDX     (WS_TOPS + (size_t)QST*NR*2*16)    // NR*Q int (256KB)
#define WS_LIST    (WS_IDX + (size_t)QST*NR*4)        // 4 stage lists x 16384 ints
#define WS_CNT     (WS_LIST + (size_t)QST*NR*4)       // 4 counters
#define WS_PART    (WS_CNT + 64)                      // 4096 f32 loss partials

__device__ __forceinline__ void gll16(const void* g, void* l) {
  __builtin_amdgcn_global_load_lds(
      (const __attribute__((address_space(1))) void*)g,
      (__attribute__((address_space(3))) void*)l, 16, 0, 0);
}

// ---- prep: per-row sumsq (+l2norm for x), fp16 hi split; combined launch ----
__global__ void prep_kernel(const float* __restrict__ x, const float* __restrict__ cb,
                            char* __restrict__ ws) {
  const int w = threadIdx.x >> 6, lane = threadIdx.x & 63;
  const int normalize = (blockIdx.x < (NR / 4));
  const int blk = normalize ? blockIdx.x : blockIdx.x - (NR / 4);
  const float* src = normalize ? x : cb;
  const int row = blk * 4 + w;
  const float4 v = ((const float4*)src)[row * 64 + lane];
  float ss = v.x * v.x + v.y * v.y + v.z * v.z + v.w * v.w;
#pragma unroll
  for (int m = 32; m; m >>= 1) ss += __shfl_xor(ss, m);
  float4 z = v;
  f16* hi;
  if (normalize) {
    const float denom = fmaxf(sqrtf(ss), 1e-12f);
    z.x = v.x / denom; z.y = v.y / denom; z.z = v.z / denom; z.w = v.w / denom;
    hi = (f16*)(ws + WS_ZN_HI);
    if (lane == 0) ((float*)(ws + WS_NORMS))[row] = denom;
    if (blockIdx.x == 0 && threadIdx.x < 4) ((int*)(ws + WS_CNT))[threadIdx.x] = 0;
  } else {
    hi = (f16*)(ws + WS_CB_HI);
    if (lane == 0) ((float*)(ws + WS_SSQ))[row] = ss;
  }
  f16x4 h;
  h[0] = (f16)z.x; h[1] = (f16)z.y; h[2] = (f16)z.z; h[3] = (f16)z.w;
  ((f16x4*)hi)[row * 64 + lane] = h;
}

// ---- score: 1-pass hi*hi GEMM + per-row top2 over K (round-1 reg shape) ----
__launch_bounds__(256, 2)
__global__ void score_kernel(char* __restrict__ ws) {
  // LDS: [0]=A_hi [1]=B_hi, each [128 rows][64 halfs] = 32 KB total
  __shared__ __align__(16) f16 smem[2][128][64];
  const int tid = threadIdx.x, w = tid >> 6, lane = tid & 63;
  const int wr = w >> 1, wc = w & 1;
  const int blk = blockIdx.x;
  const int xcd = blk & 7, st = xcd >> 1;
  const int rowtile = ((xcd & 1) << 6) + (blk >> 3);   // 0..127
  const int rowBase = rowtile << 7;

  const f16* zn_hi = (const f16*)(ws + WS_ZN_HI);
  const f16* cb_hi = (const f16*)(ws + WS_CB_HI);

  // staging roles: waves 0,1 -> A halves; waves 2,3 -> B halves
  const int reg = w >> 1;            // 0=A, 1=B
  const int half = w & 1;            // which 64-row half
  const f16* src = reg ? cb_hi : zn_hi;
  // pre-swizzled global source: LDS[row][slot] holds granule (slot ^ (row&7))
  const int g0 = (lane & 7) ^ ((lane >> 3) & 7);
  const size_t laneOff = (size_t)(lane >> 3) * DIM + (size_t)g0 * 8;
  f16* ldsW = &smem[reg][half * 64][0];

  float t1[16], t2[16]; int i1[16];
#pragma unroll
  for (int s = 0; s < 16; ++s) { t1[s] = -3.4e38f; t2[s] = -3.4e38f; i1[s] = 0; }
  const int colLane = wc * 64 + (lane & 15);

  for (int ct = 0; ct < 32; ++ct) {
    f32x4 acc[4][4];
#pragma unroll
    for (int m = 0; m < 4; ++m)
#pragma unroll
      for (int n = 0; n < 4; ++n) { acc[m][n][0] = 0.f; acc[m][n][1] = 0.f; acc[m][n][2] = 0.f; acc[m][n][3] = 0.f; }

    const int rowG0 = (reg ? (st * KCB + ct * 128) : rowBase) + half * 64;
    const f16* srcBase = src + (size_t)rowG0 * DIM + laneOff;

    for (int dc = 0; dc < 4; ++dc) {
      __syncthreads();  // protect LDS reuse from previous iteration's reads
      const f16* sp = srcBase + dc * 64;
#pragma unroll
      for (int op = 0; op < 8; ++op)
        gll16(sp + op * 8 * DIM, ldsW + op * 512);
      __syncthreads();  // compiler drains vmcnt before barrier

#pragma unroll
      for (int kk = 0; kk < 2; ++kk) {
        f16x8 ah[4];
#pragma unroll
        for (int m = 0; m < 4; ++m) {
          const int rl = wr * 64 + m * 16 + (lane & 15);
          const int slot = ((kk << 2) + (lane >> 4)) ^ (rl & 7);
          ah[m] = *(const f16x8*)(&smem[0][0][0] + rl * 64 + slot * 8);
        }
#pragma unroll
        for (int n = 0; n < 4; ++n) {
          const int cl = wc * 64 + n * 16 + (lane & 15);
          const int slot = ((kk << 2) + (lane >> 4)) ^ (cl & 7);
          const f16x8 bh = *(const f16x8*)(&smem[1][0][0] + cl * 64 + slot * 8);
#pragma unroll
          for (int m = 0; m < 4; ++m)
            acc[m][n] = __builtin_amdgcn_mfma_f32_16x16x32_f16(ah[m], bh, acc[m][n], 0, 0, 0);
        }
      }
    }
    // rank by raw dot (codebook unit-norm => ssq const to ~1e-7 << margin).
#pragma unroll
    for (int n = 0; n < 4; ++n) {
      const int col = ct * 128 + n * 16 + colLane;
#pragma unroll
      for (int m = 0; m < 4; ++m)
#pragma unroll
        for (int r = 0; r < 4; ++r) {
          const float sc = acc[m][n][r];
          const int sl = m * 4 + r;
          if (sc > t1[sl]) { t2[sl] = t1[sl]; t1[sl] = sc; i1[sl] = col; }
          else t2[sl] = fmaxf(t2[sl], sc);
        }
    }
  }

  // butterfly merge across the 16 lanes holding the same row
  float4* tops = (float4*)(ws + WS_TOPS);
#pragma unroll
  for (int m = 0; m < 4; ++m)
#pragma unroll
    for (int r = 0; r < 4; ++r) {
      const int sl = m * 4 + r;
      float a1 = t1[sl], a2 = t2[sl]; int ai = i1[sl];
#pragma unroll
      for (int msk = 1; msk < 16; msk <<= 1) {
        const float o1 = __shfl_xor(a1, msk);
        const float o2 = __shfl_xor(a2, msk);
        const int   oi = __shfl_xor(ai, msk);
        if (o1 > a1)       { a2 = fmaxf(a1, o2); a1 = o1; ai = oi; }
        else if (o1 == a1) { a2 = a1; ai = min(ai, oi); }
        else               { a2 = fmaxf(a2, o1); }
      }
      if ((lane & 15) == 0) {
        const int row = rowBase + wr * 64 + m * 16 + (lane >> 4) * 4 + r;
        tops[((size_t)st * NR + row) * 2 + wc] =
            make_float4(a1, a2, __int_as_float(ai), 0.f);
      }
    }
}

// ---- merge wave-halves, pick index, flag near-ties into per-stage lists ----
__global__ void merge_flag_kernel(char* __restrict__ ws) {
  const int t = blockIdx.x * 256 + threadIdx.x;  // t = row*4 + stage
  const int row = t >> 2, st = t & 3;
  const float4* tops = (const float4*)(ws + WS_TOPS);
  const float4 a = tops[((size_t)st * NR + row) * 2 + 0];
  const float4 b = tops[((size_t)st * NR + row) * 2 + 1];
  float v1, v2; int i1;
  if (a.x > b.x)      { v1 = a.x; v2 = fmaxf(a.y, b.x); i1 = __float_as_int(a.z); }
  else if (b.x > a.x) { v1 = b.x; v2 = fmaxf(b.y, a.x); i1 = __float_as_int(b.z); }
  else { v1 = a.x; v2 = a.x; i1 = min(__float_as_int(a.z), __float_as_int(b.z)); }
  ((int*)(ws + WS_IDX))[t] = i1;
  if (v1 - v2 < MARGIN_DOT) {
    const int p = atomicAdd((int*)(ws + WS_CNT) + st, 1);
    ((int*)(ws + WS_LIST))[(size_t)st * NR + p] = row;   // list sized NR: no drop
  }
}

// ---- exact fp32 rescue: 8 rows per codebook pass, numpy-faithful chain dot ----
__global__ void rescue_kernel(const float* __restrict__ x, const float* __restrict__ cb,
                              char* __restrict__ ws) {
  __shared__ __align__(16) float zrows[8][DIM];   // 8 KB
  __shared__ float zsqs[8];
  __shared__ float lbv[4][8];
  __shared__ int   lbi[4][8];
  const int tid = threadIdx.x, w = tid >> 6, lane = tid & 63;
  const int st = blockIdx.x & 3, slot = blockIdx.x >> 2;   // 128 slots/stage
  const int cnt = ((const int*)(ws + WS_CNT))[st];
  const int nch = (cnt + 7) >> 3;
  const int* list = (const int*)(ws + WS_LIST) + (size_t)st * NR;
  const float* cbs = cb + (size_t)st * KCB * DIM;
  const float* ssqp = (const float*)(ws + WS_SSQ) + (size_t)st * KCB;

  for (int ch = slot; ch < nch; ch += 128) {
    const int base = ch * 8;
    const int nr = min(8, cnt - base);
    // load up to 8 z-rows into LDS; thread t -> row r=t>>5, 8 elems at (t&31)*8
    const int r = tid >> 5, g = tid & 31;
    if (r < nr) {
      const int row = list[base + r];
      const float denom = ((const float*)(ws + WS_NORMS))[row];
      float ss = 0.f;
#pragma unroll
      for (int j = 0; j < 8; ++j) {
        const float v = x[(size_t)row * DIM + g * 8 + j] / denom;
        zrows[r][g * 8 + j] = v;
        ss += v * v;
      }
#pragma unroll
      for (int m = 16; m; m >>= 1) ss += __shfl_xor(ss, m);   // within 32-lane group
      if (g == 0) zsqs[r] = ss;
    }
    __syncthreads();

    float bd[8]; int bix[8];
#pragma unroll
    for (int q = 0; q < 8; ++q) { bd[q] = 3.4e38f; bix[q] = 0x7fffffff; }

    for (int k = tid; k < KCB; k += 256) {
      const float4* cr = (const float4*)(cbs + (size_t)k * DIM);
      const float4* zr = (const float4*)&zrows[0][0];
      float dot[8];
#pragma unroll
      for (int q = 0; q < 8; ++q) dot[q] = 0.f;
      for (int d = 0; d < 64; ++d) {
        const float4 cv = cr[d];
#pragma unroll
        for (int q = 0; q < 8; ++q) {
          const float4 zv = zr[q * 64 + d];   // LDS broadcast (same addr all lanes)
          dot[q] += cv.x * zv.x + cv.y * zv.y + cv.z * zv.z + cv.w * zv.w;
        }
      }
      const float sk = ssqp[k];
#pragma unroll
      for (int q = 0; q < 8; ++q) {
        const float dist = (zsqs[q] + sk) - 2.0f * dot[q];  // numpy expr order
        if (dist < bd[q]) { bd[q] = dist; bix[q] = k; }     // ascending k => min idx kept
      }
    }
    // wave-level reduce (no syncs), then cross-wave merge in LDS
#pragma unroll
    for (int q = 0; q < 8; ++q) {
#pragma unroll
      for (int m = 32; m; m >>= 1) {
        const float od = __shfl_xor(bd[q], m);
        const int   oi = __shfl_xor(bix[q], m);
        if (od < bd[q] || (od == bd[q] && oi < bix[q])) { bd[q] = od; bix[q] = oi; }
      }
      if (lane == 0) { lbv[w][q] = bd[q]; lbi[w][q] = bix[q]; }
    }
    __syncthreads();
    if (tid < 8 && tid < nr) {
      float fb = lbv[0][tid]; int fi = lbi[0][tid];
#pragma unroll
      for (int ww = 1; ww < 4; ++ww) {
        const float od = lbv[ww][tid]; const int oi = lbi[ww][tid];
        if (od < fb || (od == fb && oi < fi)) { fb = od; fi = oi; }
      }
      const int row = list[base + tid];
      ((int*)(ws + WS_IDX))[row * 4 + st] = fi;
    }
    __syncthreads();
  }
}

// ---- gather codewords, quantized sum, loss partials, indices(as float) ----
__global__ void finalize_kernel(const float* __restrict__ x, const float* __restrict__ cb,
                                char* __restrict__ ws, float* __restrict__ out) {
  __shared__ float wsum[4];
  const int w = threadIdx.x >> 6, lane = threadIdx.x & 63;
  const int row = blockIdx.x * 4 + w;
  const int* idxp = (const int*)(ws + WS_IDX) + (size_t)row * 4;
  const float denom = ((const float*)(ws + WS_NORMS))[row];
  const float4 xv = ((const float4*)x)[row * 64 + lane];
  const float4 zn = make_float4(xv.x / denom, xv.y / denom, xv.z / denom, xv.w / denom);
  float4 s = make_float4(0.f, 0.f, 0.f, 0.f);
  float lacc = 0.f;
#pragma unroll
  for (int q = 0; q < 4; ++q) {
    const int id = idxp[q];
    const float4 e = ((const float4*)(cb + ((size_t)q * KCB + id) * DIM))[lane];
    s.x += e.x; s.y += e.y; s.z += e.z; s.w += e.w;
    const float dx = e.x - zn.x, dy = e.y - zn.y, dz = e.z - zn.z, dw = e.w - zn.w;
    lacc += dx * dx + dy * dy + dz * dz + dw * dw;
  }
  ((float4*)out)[row * 64 + lane] = s;
  if (lane < 4) out[4194305 + (size_t)row * 4 + lane] = (float)idxp[lane];
#pragma unroll
  for (int m = 32; m; m >>= 1) lacc += __shfl_xor(lacc, m);
  if (lane == 0) wsum[w] = lacc;
  __syncthreads();
  if (threadIdx.x == 0)
    ((float*)(ws + WS_PART))[blockIdx.x] = wsum[0] + wsum[1] + wsum[2] + wsum[3];
}

__global__ void loss_final_kernel(const char* __restrict__ ws, float* __restrict__ out) {
  __shared__ float wsum[4];
  const int tid = threadIdx.x, w = tid >> 6, lane = tid & 63;
  const float* p = (const float*)(ws + WS_PART);
  float s = 0.f;
  for (int i = tid; i < 4096; i += 256) s += p[i];
#pragma unroll
  for (int m = 32; m; m >>= 1) s += __shfl_xor(s, m);
  if (lane == 0) wsum[w] = s;
  __syncthreads();
  if (tid == 0)
    out[4194304] = (wsum[0] + wsum[1] + wsum[2] + wsum[3]) * (1.0f / 4194304.0f);
}

extern "C" void kernel_launch(void* const* d_in, const int* in_sizes, int n_in,
                              void* d_out, int out_size, void* d_ws, size_t ws_size,
                              hipStream_t stream) {
  (void)in_sizes; (void)n_in; (void)out_size; (void)ws_size;
  const float* x = (const float*)d_in[0];
  const float* cb = (const float*)d_in[1];
  float* out = (float*)d_out;
  char* ws = (char*)d_ws;

  hipLaunchKernelGGL(prep_kernel, dim3(NR / 2), dim3(256), 0, stream, x, cb, ws);
  hipLaunchKernelGGL(score_kernel, dim3(512), dim3(256), 0, stream, ws);
  hipLaunchKernelGGL(merge_flag_kernel, dim3((NR * QST) / 256), dim3(256), 0, stream, ws);
  hipLaunchKernelGGL(rescue_kernel, dim3(512), dim3(256), 0, stream, x, cb, ws);
  hipLaunchKernelGGL(finalize_kernel, dim3(NR / 4), dim3(256), 0, stream, x, cb, ws, out);
  hipLaunchKernelGGL(loss_final_kernel, dim3(1), dim3(256), 0, stream, ws, out);
}